// Round 3
// baseline (760.953 us; speedup 1.0000x reference)
//
#include <hip/hip_runtime.h>
#include <math.h>

#define HH 128
#define WW 128
#define CG 8
#define NN 256
#define HWSZ (HH*WW)

typedef __attribute__((ext_vector_type(8))) short bf16x8;
typedef __attribute__((ext_vector_type(4))) float floatx4;

__device__ __forceinline__ float sigmoidf_(float x){ return 1.0f/(1.0f+__expf(-x)); }

__device__ __forceinline__ unsigned short f2bf(float x){
  union { float f; unsigned u; } v; v.f = x;
  unsigned r = v.u + 0x7fffu + ((v.u >> 16) & 1u);
  return (unsigned short)(r >> 16);
}
__device__ __forceinline__ float bf2f(unsigned short h){
  union { unsigned u; float f; } v; v.u = ((unsigned)h) << 16; return v.f;
}

// ---------------- Kernel A1: per-(n,c) row & column means ----------------------
__global__ __launch_bounds__(256) void kA1(const float* __restrict__ gx,
                                           float* __restrict__ xh_ws,
                                           float* __restrict__ xw_ws){
  int b = blockIdx.x; int n = b >> 3; int c = b & 7;
  int tid = threadIdx.x;
  __shared__ float colpart[2][WW];
  const float* img = gx + (size_t)(n*CG+c)*HWSZ;
  int w = tid & 127, half = tid >> 7;
  float acc = 0.f;
  const float* p = img + half*64*WW + w;
  for (int h = 0; h < 64; ++h) acc += p[h*WW];
  colpart[half][w] = acc;
  int h2 = tid >> 1, wh = tid & 1;
  float racc = 0.f;
  const float* rp = img + h2*WW + wh*64;
  for (int j = 0; j < 64; ++j) racc += rp[j];
  racc += __shfl_xor(racc, 1);
  __syncthreads();
  if (tid < WW) xw_ws[(n*CG+c)*WW + tid] = (colpart[0][tid] + colpart[1][tid]) * (1.0f/HH);
  if (wh == 0) xh_ws[(n*CG+c)*HH + h2] = racc * (1.0f/WW);
}

// ---------------- Kernel A2: 8x8 fuse conv + sigmoid ---------------------------
__global__ __launch_bounds__(256) void kA2(const float* __restrict__ xh_ws,
                                           const float* __restrict__ xw_ws,
                                           const float* __restrict__ afw,
                                           float* __restrict__ sig_h,
                                           float* __restrict__ sig_w){
  int n = blockIdx.x;
  int tid = threadIdx.x;
  if (tid < HH){
    int h = tid;
    float v[CG];
    #pragma unroll
    for (int c = 0; c < CG; ++c) v[c] = xh_ws[(n*CG+c)*HH + h];
    #pragma unroll
    for (int o = 0; o < CG; ++o){
      float s = 0.f;
      #pragma unroll
      for (int i = 0; i < CG; ++i) s = fmaf(afw[o*CG+i], v[i], s);
      sig_h[(n*CG+o)*HH + h] = sigmoidf_(s);
    }
  } else {
    int w = tid - 128;
    float v[CG];
    #pragma unroll
    for (int c = 0; c < CG; ++c) v[c] = xw_ws[(n*CG+c)*WW + w];
    #pragma unroll
    for (int o = 0; o < CG; ++o){
      float s = 0.f;
      #pragma unroll
      for (int i = 0; i < CG; ++i) s = fmaf(afw[o*CG+i], v[i], s);
      sig_w[(n*CG+o)*WW + w] = sigmoidf_(s);
    }
  }
}

// ---------------- Kernel B: GroupNorm stats of t = gx*sigh*sigw ----------------
__global__ __launch_bounds__(256) void kB(const float* __restrict__ gx,
                                          const float* __restrict__ sig_h,
                                          const float* __restrict__ sig_w,
                                          const float* __restrict__ gn_w,
                                          const float* __restrict__ gn_b,
                                          float* __restrict__ Agn,
                                          float* __restrict__ Bgn){
  int b = blockIdx.x; int n = b >> 3; int c = b & 7;
  int tid = threadIdx.x;
  __shared__ float sh[HH];
  __shared__ float swv[WW];
  __shared__ float red[16];
  if (tid < HH) sh[tid] = sig_h[(n*CG+c)*HH + tid];
  else          swv[tid-128] = sig_w[(n*CG+c)*WW + tid - 128];
  __syncthreads();
  const float* img = gx + (size_t)(n*CG+c)*HWSZ;
  float s1 = 0.f, s2 = 0.f;
  for (int idx = tid; idx < HWSZ; idx += 256){
    int h = idx >> 7, w = idx & 127;
    float t = img[idx] * sh[h] * swv[w];
    s1 += t; s2 = fmaf(t, t, s2);
  }
  #pragma unroll
  for (int off = 32; off; off >>= 1){ s1 += __shfl_down(s1, off); s2 += __shfl_down(s2, off); }
  int wv = tid >> 6, ln = tid & 63;
  if (ln == 0){ red[wv] = s1; red[8+wv] = s2; }
  __syncthreads();
  if (tid == 0){
    float S1 = red[0]+red[1]+red[2]+red[3];
    float S2 = red[8]+red[9]+red[10]+red[11];
    float mu  = S1 * (1.0f/HWSZ);
    float var = S2 * (1.0f/HWSZ) - mu*mu;
    float rstd = rsqrtf(var + 1e-5f);
    float A = rstd * gn_w[c];
    Agn[n*CG+c] = A;
    Bgn[n*CG+c] = gn_b[c] - mu*A;
  }
}

// ---------------- Kernel C: MFMA implicit-GEMM convs ---------------------------
// A (M=16) = weights: rows 0-7: sw2*w5 + sw1*w3 (+gated-tap = sw0*w1*Agn);
//            rows 8-15: raw w3.  B (N=16) = pixels, K = 4 taps x 8 ic.
// D rows 0-7 -> x1 (minus const), rows 8-15 -> x2.
__global__ __launch_bounds__(256) void kC(const float* __restrict__ gx,
                                          const float* __restrict__ w1,
                                          const float* __restrict__ w3,
                                          const float* __restrict__ w5,
                                          const float* __restrict__ scale_w,
                                          const float* __restrict__ spw,
                                          const float* __restrict__ sig_h,
                                          const float* __restrict__ sig_w,
                                          const float* __restrict__ Agn,
                                          const float* __restrict__ Bgn,
                                          unsigned short* __restrict__ x1m,
                                          unsigned short* __restrict__ x2m,
                                          float* __restrict__ gacc){
  // [0,10368): tile 36x36 pixels x 8 ic (bf16);  [10368,18560): gated 32x32x8
  __shared__ __align__(16) short lds[18560];
  __shared__ float sighs[32][8];
  __shared__ float sigws[32][8];
  __shared__ float wred[4][32];

  int tid = threadIdx.x;
  int lane = tid & 63, wave = tid >> 6;
  int m = lane & 15, quad = lane >> 4;
  int bb = blockIdx.x;
  int nb = bb >> 4;
  int t_ = bb & 15;
  int y0 = (t_ >> 2) * 32, x0 = (t_ & 3) * 32;

  float sw0, sw1, sw2;
  { float a=scale_w[0], b=scale_w[1], c=scale_w[2];
    float mx=fmaxf(a,fmaxf(b,c));
    float e0=__expf(a-mx), e1=__expf(b-mx), e2=__expf(c-mx);
    float inv=1.f/(e0+e1+e2); sw0=e0*inv; sw1=e1*inv; sw2=e2*inv; }

  // ---- stage input tile: [pixel][ic] bf16, dword = ic-pair -> linear, conflict-free
  const float* base_n = gx + (size_t)nb*CG*HWSZ;
  for (int idx = tid; idx < 36*36*4; idx += 256){
    int p = idx >> 2, q = idx & 3;
    int yy = p / 36, xx = p - yy*36;
    int gy = y0 + yy - 2, gxx = x0 + xx - 2;
    float lo = 0.f, hi = 0.f;
    if (gy >= 0 && gy < HH && gxx >= 0 && gxx < WW){
      lo = base_n[(size_t)(2*q)*HWSZ + gy*WW + gxx];
      hi = base_n[(size_t)(2*q+1)*HWSZ + gy*WW + gxx];
    }
    ((unsigned*)lds)[idx] = (unsigned)f2bf(lo) | ((unsigned)f2bf(hi) << 16);
  }
  { // sigma staging, transposed [pos][ic] so gated staging reads spread banks
    int yy = tid >> 3, ic = tid & 7;
    sighs[yy][ic] = sig_h[(nb*CG+ic)*HH + y0 + yy];
    sigws[yy][ic] = sig_w[(nb*CG+ic)*WW + x0 + yy];
  }

  // ---- A fragments (per lane, once): tap t = 4*i + quad ----
  bf16x8 afr[7];
  int toff[7];
  #pragma unroll 1
  for (int i = 0; i < 7; ++i){
    int t = 4*i + quad;
    float av[8];
    #pragma unroll
    for (int j = 0; j < 8; ++j) av[j] = 0.f;
    if (t < 25){
      int dy = t/5, dx = t%5;
      bool inner = (dy>=1 && dy<=3 && dx>=1 && dx<=3);
      int k3 = (dy-1)*3 + (dx-1);
      if (m < 8){
        #pragma unroll
        for (int j = 0; j < 8; ++j){
          float wv = sw2 * w5[m*200 + j*25 + t];
          if (inner) wv += sw1 * w3[m*72 + j*9 + k3];
          av[j] = wv;
        }
      } else if (inner){
        #pragma unroll
        for (int j = 0; j < 8; ++j) av[j] = w3[(m-8)*72 + j*9 + k3];
      }
      toff[i] = (dy*36 + dx)*8;
    } else {
      if (t == 25 && m < 8){   // gated 1x1 path: coefA = sw0*w1*Agn
        #pragma unroll
        for (int j = 0; j < 8; ++j) av[j] = sw0 * w1[m*CG+j] * Agn[nb*CG+j];
      }
      toff[i] = 0;
    }
    bf16x8 af;
    #pragma unroll
    for (int j = 0; j < 8; ++j) af[j] = (short)f2bf(av[j]);
    afr[i] = af;
  }

  // const term (x1 rows only)
  float cst[4] = {0.f,0.f,0.f,0.f};
  if (quad < 2){
    #pragma unroll
    for (int r = 0; r < 4; ++r){
      int oc = quad*4 + r;
      float s = 0.f;
      #pragma unroll
      for (int j = 0; j < 8; ++j) s = fmaf(w1[oc*CG+j], Bgn[nb*CG+j], s);
      cst[r] = sw0 * s;
    }
  }
  float spv[4];
  #pragma unroll
  for (int r = 0; r < 4; ++r) spv[r] = spw[(quad&1)*4 + r];

  __syncthreads();

  // ---- build gated tile: gx * sigh[ic] * sigw[ic], bf16 ----
  for (int idx = tid; idx < 32*32*4; idx += 256){
    int p = idx >> 2, q = idx & 3;
    int yy = p >> 5, xx = p & 31;
    unsigned d = ((const unsigned*)lds)[((yy+2)*36 + (xx+2))*4 + q];
    float lo = bf2f((unsigned short)(d & 0xffffu)) * sighs[yy][2*q]   * sigws[xx][2*q];
    float hi = bf2f((unsigned short)(d >> 16))     * sighs[yy][2*q+1] * sigws[xx][2*q+1];
    ((unsigned*)lds)[5184 + idx] = (unsigned)f2bf(lo) | ((unsigned)f2bf(hi) << 16);
  }
  __syncthreads();

  // ---- chunk loop: 64 chunks of 16 pixels (row y, x-half) ----
  float sums[4] = {0,0,0,0}, sumq[4] = {0,0,0,0};
  unsigned short* opx = (quad < 2) ? x1m : x2m;
  size_t pbase0 = ((size_t)(nb*CG + (quad&1)*4))*HWSZ;
  bool g6 = (quad == 1);   // tap 25 (gated) lives in mfma #6, quad 1

  for (int c = wave; c < 64; c += 4){
    int y = c >> 1, xh = (c & 1) << 4;
    int pxl = xh + m;
    int cb_t = (y*36 + pxl)*8;
    int cb_g = 10368 + (y*32 + pxl)*8;
    floatx4 acc = {0.f,0.f,0.f,0.f};
    #pragma unroll
    for (int i = 0; i < 6; ++i){
      bf16x8 bfr = *(const bf16x8*)(lds + cb_t + toff[i]);
      acc = __builtin_amdgcn_mfma_f32_16x16x32_bf16(afr[i], bfr, acc, 0, 0, 0);
    }
    {
      int off6 = g6 ? cb_g : (cb_t + toff[6]);
      bf16x8 bfr = *(const bf16x8*)(lds + off6);
      acc = __builtin_amdgcn_mfma_f32_16x16x32_bf16(afr[6], bfr, acc, 0, 0, 0);
    }
    float v[4];
    #pragma unroll
    for (int r = 0; r < 4; ++r) v[r] = acc[r] + cst[r];
    float s = 0.f;
    #pragma unroll
    for (int r = 0; r < 4; ++r) s = fmaf(spv[r], v[r], s);
    s += __shfl_xor(s, 16);          // quad0+quad1 -> s1 ; quad2+quad3 -> s2
    float sp = sigmoidf_(s);
    #pragma unroll
    for (int r = 0; r < 4; ++r){ sums[r] += v[r]; sumq[r] = fmaf(v[r], sp, sumq[r]); }
    size_t pb = pbase0 + (size_t)(y0 + y)*WW + (x0 + pxl);
    #pragma unroll
    for (int r = 0; r < 4; ++r) opx[pb + (size_t)r*HWSZ] = f2bf(v[r]);
  }

  // ---- reduce gate sums across pixel lanes, then waves, then atomics ----
  #pragma unroll
  for (int off = 1; off < 16; off <<= 1){
    #pragma unroll
    for (int r = 0; r < 4; ++r){
      sums[r] += __shfl_xor(sums[r], off);
      sumq[r] += __shfl_xor(sumq[r], off);
    }
  }
  if ((lane & 15) == 0){
    int base = (quad >= 2 ? 16 : 0) + (quad & 1)*4;
    #pragma unroll
    for (int r = 0; r < 4; ++r){
      wred[wave][base + r]     = sums[r];
      wred[wave][base + 8 + r] = sumq[r];
    }
  }
  __syncthreads();
  if (tid < 32){
    float s = wred[0][tid] + wred[1][tid] + wred[2][tid] + wred[3][tid];
    atomicAdd(&gacc[nb*32 + tid], s);
  }
}

// ---------------- Kernel T: channel gates + softmaxes -> a1,a2 -----------------
__global__ void kT(const float* __restrict__ gacc, const float* __restrict__ cgw,
                   float* __restrict__ a1a2){
  int n = blockIdx.x*blockDim.x + threadIdx.x;
  if (n >= NN) return;
  const float* g = gacc + n*32;
  float m1[CG], q1[CG], m2[CG], q2[CG];
  #pragma unroll
  for (int c = 0; c < CG; ++c){
    m1[c] = g[c]    * (1.0f/HWSZ);
    q1[c] = g[8+c]  * (1.0f/HWSZ);
    m2[c] = g[16+c] * (1.0f/HWSZ);
    q2[c] = g[24+c] * (1.0f/HWSZ);
  }
  float chg1[CG], chg2[CG];
  #pragma unroll
  for (int o = 0; o < CG; ++o){
    float s1 = 0.f, s2 = 0.f;
    #pragma unroll
    for (int i = 0; i < CG; ++i){ s1 = fmaf(cgw[o*CG+i], m1[i], s1); s2 = fmaf(cgw[o*CG+i], m2[i], s2); }
    chg1[o] = sigmoidf_(s1); chg2[o] = sigmoidf_(s2);
  }
  float z1[CG], z2[CG];
  float mx1 = -1e30f, mx2 = -1e30f;
  #pragma unroll
  for (int c = 0; c < CG; ++c){
    z1[c] = chg1[c]*q1[c]; z2[c] = chg2[c]*q2[c];
    mx1 = fmaxf(mx1, z1[c]); mx2 = fmaxf(mx2, z2[c]);
  }
  float su1 = 0.f, su2 = 0.f;
  #pragma unroll
  for (int c = 0; c < CG; ++c){
    z1[c] = __expf(z1[c]-mx1); su1 += z1[c];
    z2[c] = __expf(z2[c]-mx2); su2 += z2[c];
  }
  float i1 = 1.0f/su1, i2 = 1.0f/su2;
  #pragma unroll
  for (int c = 0; c < CG; ++c){
    float x11 = z1[c]*i1;
    float x21 = z2[c]*i2;
    a1a2[n*16 + c]     = x21 * chg1[c];
    a1a2[n*16 + 8 + c] = x11 * chg2[c];
  }
}

// ---------------- Kernel F: final weights + output (4 px / thread) -------------
__global__ __launch_bounds__(256) void kF(const float* __restrict__ gx,
                                          const unsigned short* __restrict__ x1m,
                                          const unsigned short* __restrict__ x2m,
                                          const float* __restrict__ a1a2,
                                          const float* __restrict__ spw,
                                          float* __restrict__ out){
  int tid = threadIdx.x;
  int bb = blockIdx.x;            // NN*16 blocks
  int n = bb >> 4;
  int p4 = ((bb & 15) << 8) + tid;
  size_t base = (size_t)n*CG*HWSZ + (size_t)p4*4;
  float a1[CG], a2[CG], sp[CG];
  #pragma unroll
  for (int c = 0; c < CG; ++c){
    a1[c] = a1a2[n*16 + c];
    a2[c] = a1a2[n*16 + 8 + c];
    sp[c] = spw[c];
  }
  float d1[4]={0,0,0,0}, dd1[4]={0,0,0,0}, d2[4]={0,0,0,0}, dd2[4]={0,0,0,0};
  #pragma unroll
  for (int c = 0; c < CG; ++c){
    ushort4 u1 = *(const ushort4*)(x1m + base + (size_t)c*HWSZ);
    ushort4 u2 = *(const ushort4*)(x2m + base + (size_t)c*HWSZ);
    float v1[4] = {bf2f(u1.x), bf2f(u1.y), bf2f(u1.z), bf2f(u1.w)};
    float v2[4] = {bf2f(u2.x), bf2f(u2.y), bf2f(u2.z), bf2f(u2.w)};
    #pragma unroll
    for (int p = 0; p < 4; ++p){
      d1[p]  = fmaf(sp[c], v1[p], d1[p]);  dd1[p] = fmaf(a1[c], v1[p], dd1[p]);
      d2[p]  = fmaf(sp[c], v2[p], d2[p]);  dd2[p] = fmaf(a2[c], v2[p], dd2[p]);
    }
  }
  float sW[4];
  #pragma unroll
  for (int p = 0; p < 4; ++p)
    sW[p] = sigmoidf_(sigmoidf_(d1[p])*dd1[p] + sigmoidf_(d2[p])*dd2[p]);
  #pragma unroll
  for (int c = 0; c < CG; ++c){
    float4 g = *(const float4*)(gx + base + (size_t)c*HWSZ);
    float4 o; o.x = g.x*sW[0]; o.y = g.y*sW[1]; o.z = g.z*sW[2]; o.w = g.w*sW[3];
    *(float4*)(out + base + (size_t)c*HWSZ) = o;
  }
}

extern "C" void kernel_launch(void* const* d_in, const int* in_sizes, int n_in,
                              void* d_out, int out_size, void* d_ws, size_t ws_size,
                              hipStream_t stream){
  const float* x   = (const float*)d_in[0];
  const float* afw = (const float*)d_in[1];
  const float* gnw = (const float*)d_in[2];
  const float* gnb = (const float*)d_in[3];
  const float* w1  = (const float*)d_in[4];
  const float* w3  = (const float*)d_in[5];
  const float* w5  = (const float*)d_in[6];
  const float* scw = (const float*)d_in[7];
  const float* cgw = (const float*)d_in[8];
  const float* spw = (const float*)d_in[9];

  char* ws = (char*)d_ws;
  float* sig_h = (float*)(ws + 0);               // 1 MiB
  float* sig_w = (float*)(ws + 1048576);         // 1 MiB
  float* Agn   = (float*)(ws + 2097152);         // 8 KiB
  float* Bgn   = (float*)(ws + 2105344);         // 8 KiB
  float* gacc  = (float*)(ws + 2113536);         // 32 KiB
  float* a1a2  = (float*)(ws + 2146304);         // 16 KiB
  unsigned short* x1m = (unsigned short*)(ws + 2162688);            // 64 MiB
  unsigned short* x2m = (unsigned short*)(ws + 2162688 + 67108864); // 64 MiB
  float* out = (float*)d_out;
  // xh/xw staging lives in d_out (dead before kF writes it)
  float* xh_ws = (float*)d_out;                  // 1 MiB
  float* xw_ws = (float*)d_out + 262144;         // 1 MiB

  hipMemsetAsync(gacc, 0, NN*32*sizeof(float), stream);
  kA1<<<NN*CG, 256, 0, stream>>>(x, xh_ws, xw_ws);
  kA2<<<NN, 256, 0, stream>>>(xh_ws, xw_ws, afw, sig_h, sig_w);
  kB <<<NN*CG, 256, 0, stream>>>(x, sig_h, sig_w, gnw, gnb, Agn, Bgn);
  kC <<<NN*16, 256, 0, stream>>>(x, w1, w3, w5, scw, spw, sig_h, sig_w, Agn, Bgn, x1m, x2m, gacc);
  kT <<<4, 64, 0, stream>>>(gacc, cgw, a1a2);
  kF <<<NN*16, 256, 0, stream>>>(x, x1m, x2m, a1a2, spw, out);
}